// Round 2
// baseline (537.956 us; speedup 1.0000x reference)
//
#include <hip/hip_runtime.h>
#include <hip/hip_bf16.h>
#include <stdint.h>

// ---------------------------------------------------------------------------
// Self-attention, B=4 S=2048 D=1024, fp32 in/out, fp16 MFMA compute
// (fp16 over bf16: 11-bit mantissa needed to meet the 5.9e-2 absmax bar;
//  bf16 version measured absmax 0.134).
// Pipeline:
//   1) q = x@Wq^T, k = x@Wk^T (fp16 out, row-major [B*S, D])
//      v written TRANSPOSED per batch: vt[b][d][s]  (so PV is a bt-GEMM too)
//   2) per batch: scores = q_b @ k_b^T  (fp32, 2048x2048, buffer reused)
//   3) per batch: softmax rows -> attn (fp16)
//   4) per batch: out_b = attn @ vt_b^T (fp32) -> d_out
// One GEMM skeleton: C = A * B^T, 128x128 tile, BK=32, 4 waves (2x2), each
// wave 64x64 via 4x4 MFMA 16x16x32_f16 tiles. All dims divide tile sizes,
// so no bounds checks.
// ---------------------------------------------------------------------------

#define TILE 128
#define BK   32
#define LSTR (BK + 8)   // +8 halves = +16B pad to break power-of-2 bank stride

typedef __attribute__((ext_vector_type(8))) _Float16 f16x8;
typedef __attribute__((ext_vector_type(4))) float f32x4;

__device__ inline unsigned short f2h(float f) {
    union { _Float16 h; unsigned short u; } x;
    x.h = (_Float16)f;   // RNE
    return x.u;
}

template <bool IN_F32, bool OUT_F32, bool TRANS_OUT>
__global__ __launch_bounds__(256)
void gemm_bt(const void* __restrict__ Ap, const void* __restrict__ Bp,
             void* __restrict__ Cp, int M, int N, int K)
{
    __shared__ unsigned short As[TILE * LSTR];
    __shared__ unsigned short Bs[TILE * LSTR];

    const int tid  = threadIdx.x;
    const int lane = tid & 63;
    const int wave = tid >> 6;
    const int wr   = wave >> 1, wc = wave & 1;   // 2x2 wave grid
    const int quad = lane >> 4, lrow = lane & 15;
    const int bm   = blockIdx.y, bn = blockIdx.x;

    f32x4 acc[4][4];
#pragma unroll
    for (int i = 0; i < 4; ++i)
#pragma unroll
        for (int j = 0; j < 4; ++j)
            acc[i][j] = f32x4{0.f, 0.f, 0.f, 0.f};

    // staging map: thread t covers 8 contiguous k-elements; 2 passes cover
    // 128 rows x 32 cols for both A and B tiles.
    const int g_row0 = tid >> 2;         // 0..63
    const int g_col  = (tid & 3) * 8;    // 0,8,16,24

    for (int k0 = 0; k0 < K; k0 += BK) {
#pragma unroll
        for (int p = 0; p < 2; ++p) {
            const int row = g_row0 + p * 64;
            const long offA = (long)(bm * TILE + row) * K + k0 + g_col;
            const long offB = (long)(bn * TILE + row) * K + k0 + g_col;
            if (IN_F32) {
                const float* a = (const float*)Ap + offA;
                const float* b = (const float*)Bp + offB;
                f32x4 a0 = *(const f32x4*)a;
                f32x4 a1 = *(const f32x4*)(a + 4);
                f32x4 b0 = *(const f32x4*)b;
                f32x4 b1 = *(const f32x4*)(b + 4);
                union { unsigned short u[8]; f16x8 v; } ta, tb;
#pragma unroll
                for (int i = 0; i < 4; ++i) {
                    ta.u[i]     = f2h(a0[i]);
                    ta.u[4 + i] = f2h(a1[i]);
                    tb.u[i]     = f2h(b0[i]);
                    tb.u[4 + i] = f2h(b1[i]);
                }
                *(f16x8*)&As[row * LSTR + g_col] = ta.v;
                *(f16x8*)&Bs[row * LSTR + g_col] = tb.v;
            } else {
                *(f16x8*)&As[row * LSTR + g_col] =
                    *(const f16x8*)((const unsigned short*)Ap + offA);
                *(f16x8*)&Bs[row * LSTR + g_col] =
                    *(const f16x8*)((const unsigned short*)Bp + offB);
            }
        }
        __syncthreads();

        f16x8 af[4], bfr[4];
#pragma unroll
        for (int mt = 0; mt < 4; ++mt)
            af[mt] = *(const f16x8*)&As[(wr * 64 + mt * 16 + lrow) * LSTR + quad * 8];
#pragma unroll
        for (int nt = 0; nt < 4; ++nt)
            bfr[nt] = *(const f16x8*)&Bs[(wc * 64 + nt * 16 + lrow) * LSTR + quad * 8];
#pragma unroll
        for (int mt = 0; mt < 4; ++mt)
#pragma unroll
            for (int nt = 0; nt < 4; ++nt)
                acc[mt][nt] = __builtin_amdgcn_mfma_f32_16x16x32_f16(
                    af[mt], bfr[nt], acc[mt][nt], 0, 0, 0);
        __syncthreads();
    }

    // epilogue: C/D layout col = lane&15, row = quad*4 + reg
    const int row_base = bm * TILE + wr * 64;
    const int col_base = bn * TILE + wc * 64;
#pragma unroll
    for (int mt = 0; mt < 4; ++mt) {
#pragma unroll
        for (int nt = 0; nt < 4; ++nt) {
#pragma unroll
            for (int r = 0; r < 4; ++r) {
                const int row = row_base + mt * 16 + quad * 4 + r;
                const int col = col_base + nt * 16 + lrow;
                const float v = acc[mt][nt][r];
                if (OUT_F32) {
                    ((float*)Cp)[(long)row * N + col] = v;
                } else if (!TRANS_OUT) {
                    ((unsigned short*)Cp)[(long)row * N + col] = f2h(v);
                } else {
                    // vt[b][col][s], b = row/2048, s = row%2048, ld = 2048
                    const int b = row >> 11;
                    const int s = row & 2047;
                    ((unsigned short*)Cp)[((long)b * N + col) * 2048 + s] = f2h(v);
                }
            }
        }
    }
}

// one block per row; ncol must be 2048 (8 elems/thread at 256 threads)
__global__ __launch_bounds__(256)
void softmax_rows(const float* __restrict__ S_, unsigned short* __restrict__ P,
                  int ncol)
{
    const int row = blockIdx.x;
    const int tid = threadIdx.x;
    const float* srow = S_ + (long)row * ncol;

    float vals[8];
    float m = -1e30f;
#pragma unroll
    for (int i = 0; i < 8; ++i) {
        vals[i] = srow[tid + i * 256];
        m = fmaxf(m, vals[i]);
    }
#pragma unroll
    for (int off = 32; off; off >>= 1) m = fmaxf(m, __shfl_xor(m, off));

    __shared__ float redm[4];
    __shared__ float reds[4];
    if ((tid & 63) == 0) redm[tid >> 6] = m;
    __syncthreads();
    m = fmaxf(fmaxf(redm[0], redm[1]), fmaxf(redm[2], redm[3]));

    float s = 0.f;
#pragma unroll
    for (int i = 0; i < 8; ++i) {
        vals[i] = __expf(vals[i] - m);
        s += vals[i];
    }
#pragma unroll
    for (int off = 32; off; off >>= 1) s += __shfl_xor(s, off);
    if ((tid & 63) == 0) reds[tid >> 6] = s;
    __syncthreads();
    s = reds[0] + reds[1] + reds[2] + reds[3];

    const float inv = 1.f / s;
#pragma unroll
    for (int i = 0; i < 8; ++i)
        P[(long)row * ncol + tid + i * 256] = f2h(vals[i] * inv);
}

extern "C" void kernel_launch(void* const* d_in, const int* in_sizes, int n_in,
                              void* d_out, int out_size, void* d_ws, size_t ws_size,
                              hipStream_t stream)
{
    const float* x  = (const float*)d_in[0];
    const float* wq = (const float*)d_in[1];
    const float* wk = (const float*)d_in[2];
    const float* wv = (const float*)d_in[3];
    float* out = (float*)d_out;

    const int Bb = 4, S = 2048, D = 1024;
    const long tokD = (long)Bb * S * D;  // 8388608

    // workspace layout (72 MB total)
    unsigned short* q    = (unsigned short*)d_ws;     // fp16 [B*S, D]
    unsigned short* k    = q + tokD;                  // fp16 [B*S, D]
    unsigned short* vt   = k + tokD;                  // fp16 [B][D][S]
    float*          sc   = (float*)(vt + tokD);       // fp32 [S, S] (reused)
    unsigned short* attn = (unsigned short*)(sc + (long)S * S);  // fp16 [S,S]

    dim3 blk(256);

    // 1) projections: M = B*S = 8192, N = D, K = D
    dim3 gp(D / TILE, (Bb * S) / TILE);
    gemm_bt<true, false, false><<<gp, blk, 0, stream>>>(x, wq, q, Bb * S, D, D);
    gemm_bt<true, false, false><<<gp, blk, 0, stream>>>(x, wk, k, Bb * S, D, D);
    gemm_bt<true, false, true ><<<gp, blk, 0, stream>>>(x, wv, vt, Bb * S, D, D);

    for (int b = 0; b < Bb; ++b) {
        const unsigned short* qb  = q  + (long)b * S * D;
        const unsigned short* kb  = k  + (long)b * S * D;
        const unsigned short* vtb = vt + (long)b * D * S;

        // 2) scores = q_b @ k_b^T : M=S, N=S, K=D
        dim3 gs(S / TILE, S / TILE);
        gemm_bt<false, true, false><<<gs, blk, 0, stream>>>(qb, kb, sc, S, S, D);

        // 3) softmax rows -> attn fp16
        softmax_rows<<<dim3(S), blk, 0, stream>>>(sc, attn, S);

        // 4) out_b = attn @ vt_b^T : M=S, N=D, K=S
        dim3 ga(D / TILE, S / TILE);
        gemm_bt<false, true, false><<<ga, blk, 0, stream>>>(
            attn, vtb, out + (long)b * S * D, S, D, S);
    }
}

// Round 3
// 328.754 us; speedup vs baseline: 1.6363x; 1.6363x over previous
//
#include <hip/hip_runtime.h>
#include <hip/hip_bf16.h>
#include <stdint.h>

// ---------------------------------------------------------------------------
// Self-attention, B=4 S=2048 D=1024, fp32 in/out, fp16 MFMA compute.
//   0) convert x -> xh (fp16), w_q/w_k/w_v -> wh (fp16, packed)
//   1) q,k = xh @ {wq,wk}^T   (one launch, grid.z=2, fp16 out)
//      vt  = (xh @ wv^T)^T    (LDS-transpose epilogue -> vt[b][d][s], fp16)
//   2) scores = q_b @ k_b^T   (fp32, batched over z if ws allows)
//   3) softmax rows IN PLACE  (fp32 row -> fp16 row at same base, pitch 4096h)
//   4) out_b = attn_b @ vt_b^T (fp32 -> d_out)
// GEMM: m97-style. 128x128 tile, BK=32, 4 waves (2x2), 4x4 MFMA 16x16x32_f16
// per wave. global_load_lds width=16 staging (LDS unpadded, XOR-swizzled
// chunks so frag ds_read_b128 is bank-conflict-free). 2-barrier K-loop.
// ---------------------------------------------------------------------------

typedef __attribute__((ext_vector_type(8))) _Float16 f16x8;
typedef __attribute__((ext_vector_type(4))) float f32x4;
typedef __attribute__((ext_vector_type(4))) unsigned short u16x4;

__device__ inline unsigned short f2h(float f) {
    union { _Float16 h; unsigned short u; } x;
    x.h = (_Float16)f;   // RNE
    return x.u;
}

__device__ inline void async16(const unsigned short* g, unsigned short* l) {
    __builtin_amdgcn_global_load_lds(
        (__attribute__((address_space(1))) void*)g,
        (__attribute__((address_space(3))) void*)l, 16, 0, 0);
}

// OUTMODE: 0 = fp16 row-major, 1 = fp16 transposed (vt, LDS transpose),
//          2 = fp32 row-major
template <int OUTMODE>
__global__ __launch_bounds__(256)
void gemm16(const unsigned short* __restrict__ A,
            const unsigned short* __restrict__ B,
            void* __restrict__ C, int K,
            int ldA, int ldB, int ldC,
            long sAz, long sBz, long sCz)
{
    __shared__ unsigned short As[128 * 32];
    __shared__ unsigned short Bs[128 * 32];

    const int tid  = threadIdx.x;
    const int lane = tid & 63;
    const int wave = tid >> 6;
    const int wr   = wave >> 1, wc = wave & 1;
    const int quad = lane >> 4, lrow = lane & 15;
    const int bm   = blockIdx.y, bn = blockIdx.x, z = blockIdx.z;

    const unsigned short* Az = A + (long)z * sAz;
    const unsigned short* Bz = B + (long)z * sBz;

    // staging source pointers: chunk l (16B) -> row l>>2, phys chunk l&3,
    // holding logical k-chunk (l&3) ^ ((row>>1)&3)  (XOR swizzle)
    const int l0 = tid, l1 = 256 + tid;
    const int rA0 = l0 >> 2, cA0 = (l0 & 3) ^ ((rA0 >> 1) & 3);
    const int rA1 = l1 >> 2, cA1 = (l1 & 3) ^ ((rA1 >> 1) & 3);
    const unsigned short* gA0 = Az + (long)(bm * 128 + rA0) * ldA + cA0 * 8;
    const unsigned short* gA1 = Az + (long)(bm * 128 + rA1) * ldA + cA1 * 8;
    const unsigned short* gB0 = Bz + (long)(bn * 128 + rA0) * ldB + cA0 * 8;
    const unsigned short* gB1 = Bz + (long)(bn * 128 + rA1) * ldB + cA1 * 8;

    f32x4 acc[4][4];
#pragma unroll
    for (int i = 0; i < 4; ++i)
#pragma unroll
        for (int j = 0; j < 4; ++j)
            acc[i][j] = f32x4{0.f, 0.f, 0.f, 0.f};

    // fragment read: logical chunk = quad, phys = quad ^ ((row>>1)&3);
    // (row>>1)&3 == (lrow>>1)&3 since mt*16 and w*64 are 0 mod 8.
    const int phys_off = (quad ^ ((lrow >> 1) & 3)) * 8;

    for (int k0 = 0; k0 < K; k0 += 32) {
        async16(gA0, &As[l0 * 8]);
        async16(gA1, &As[l1 * 8]);
        async16(gB0, &Bs[l0 * 8]);
        async16(gB1, &Bs[l1 * 8]);
        gA0 += 32; gA1 += 32; gB0 += 32; gB1 += 32;
        __syncthreads();   // drains vmcnt -> tiles visible in LDS

        f16x8 af[4], bf[4];
#pragma unroll
        for (int mt = 0; mt < 4; ++mt)
            af[mt] = *(const f16x8*)&As[(wr * 64 + mt * 16 + lrow) * 32 + phys_off];
#pragma unroll
        for (int nt = 0; nt < 4; ++nt)
            bf[nt] = *(const f16x8*)&Bs[(wc * 64 + nt * 16 + lrow) * 32 + phys_off];
#pragma unroll
        for (int mt = 0; mt < 4; ++mt)
#pragma unroll
            for (int nt = 0; nt < 4; ++nt)
                acc[mt][nt] = __builtin_amdgcn_mfma_f32_16x16x32_f16(
                    af[mt], bf[nt], acc[mt][nt], 0, 0, 0);
        __syncthreads();   // LDS free before next tile's async writes
    }

    const int col_base = bn * 128 + wc * 64;

    if (OUTMODE == 0 || OUTMODE == 2) {
        const int row_base = bm * 128 + wr * 64;
        const long zC = (long)z * sCz;
#pragma unroll
        for (int mt = 0; mt < 4; ++mt)
#pragma unroll
            for (int nt = 0; nt < 4; ++nt)
#pragma unroll
                for (int r = 0; r < 4; ++r) {
                    const int row = row_base + mt * 16 + quad * 4 + r;
                    const int col = col_base + nt * 16 + lrow;
                    if (OUTMODE == 2)
                        ((float*)C)[zC + (long)row * ldC + col] = acc[mt][nt][r];
                    else
                        ((unsigned short*)C)[zC + (long)row * ldC + col] =
                            f2h(acc[mt][nt][r]);
                }
    } else {
        // vt transpose: T[col 128][row 64], pitch 72 halves (pad: bank spread
        // + keeps 16B alignment: 144B rows)
        __shared__ unsigned short T[128 * 72];
#pragma unroll
        for (int p = 0; p < 2; ++p) {
            __syncthreads();
            if (wr == p) {
#pragma unroll
                for (int mt = 0; mt < 4; ++mt)
#pragma unroll
                    for (int nt = 0; nt < 4; ++nt) {
                        const int row_l = mt * 16 + quad * 4;
                        const int col_l = wc * 64 + nt * 16 + lrow;
                        u16x4 pk = {f2h(acc[mt][nt][0]), f2h(acc[mt][nt][1]),
                                    f2h(acc[mt][nt][2]), f2h(acc[mt][nt][3])};
                        *(u16x4*)&T[col_l * 72 + row_l] = pk;
                    }
            }
            __syncthreads();
            // copy out: thread covers 32 halves of one d-row
            const int c  = tid >> 1;
            const int j0 = (tid & 1) * 32;
            const int tok0 = bm * 128 + p * 64;        // global token start
            const int bb = tok0 >> 11;                 // batch (S=2048)
            const int s0 = (tok0 & 2047) + j0;
            unsigned short* dst = (unsigned short*)C + (long)bb * sCz +
                                  (long)(col_base - wc * 64 + c) * 0; // placate
            dst = (unsigned short*)C + (long)bb * sCz +
                  (long)(bn * 128 + c) * ldC + s0;
            const unsigned short* srcT = &T[c * 72 + j0];
#pragma unroll
            for (int i = 0; i < 4; ++i)
                *(f16x8*)(dst + i * 8) = *(const f16x8*)(srcT + i * 8);
        }
    }
}

// fp32 -> fp16, 8 elems/thread, exact grid
__global__ __launch_bounds__(256)
void cvt1(const float* __restrict__ s, unsigned short* __restrict__ d)
{
    const long i = ((long)blockIdx.x * 256 + threadIdx.x) * 8;
    f32x4 a = *(const f32x4*)(s + i);
    f32x4 b = *(const f32x4*)(s + i + 4);
    union { unsigned short u[8]; f16x8 v; } t;
#pragma unroll
    for (int j = 0; j < 4; ++j) { t.u[j] = f2h(a[j]); t.u[4 + j] = f2h(b[j]); }
    *(f16x8*)(d + i) = t.v;
}

// 3 weights -> packed wh
__global__ __launch_bounds__(256)
void cvt3(const float* __restrict__ s0, const float* __restrict__ s1,
          const float* __restrict__ s2, unsigned short* __restrict__ d)
{
    const int z = blockIdx.z;
    const float* s = (z == 0) ? s0 : (z == 1) ? s1 : s2;
    const long i = ((long)blockIdx.x * 256 + threadIdx.x) * 8;
    f32x4 a = *(const f32x4*)(s + i);
    f32x4 b = *(const f32x4*)(s + i + 4);
    union { unsigned short u[8]; f16x8 v; } t;
#pragma unroll
    for (int j = 0; j < 4; ++j) { t.u[j] = f2h(a[j]); t.u[4 + j] = f2h(b[j]); }
    *(f16x8*)(d + (long)z * 1048576 + i) = t.v;
}

// in-place row softmax: reads 2048 fp32, writes 2048 fp16 at same row base.
// All reads land in regs before the first barrier -> in-place is safe.
__global__ __launch_bounds__(256)
void softmax_ip(float* __restrict__ sc)
{
    const long row = blockIdx.x;
    float* srow = sc + row * 2048;
    const int tid = threadIdx.x;

    f32x4 a = *(const f32x4*)(srow + tid * 8);
    f32x4 b = *(const f32x4*)(srow + tid * 8 + 4);
    float v[8];
#pragma unroll
    for (int i = 0; i < 4; ++i) { v[i] = a[i]; v[4 + i] = b[i]; }

    float m = v[0];
#pragma unroll
    for (int i = 1; i < 8; ++i) m = fmaxf(m, v[i]);
#pragma unroll
    for (int off = 32; off; off >>= 1) m = fmaxf(m, __shfl_xor(m, off));

    __shared__ float redm[4], reds[4];
    if ((tid & 63) == 0) redm[tid >> 6] = m;
    __syncthreads();
    m = fmaxf(fmaxf(redm[0], redm[1]), fmaxf(redm[2], redm[3]));

    float s = 0.f;
#pragma unroll
    for (int i = 0; i < 8; ++i) { v[i] = __expf(v[i] - m); s += v[i]; }
#pragma unroll
    for (int off = 32; off; off >>= 1) s += __shfl_xor(s, off);
    if ((tid & 63) == 0) reds[tid >> 6] = s;
    __syncthreads();
    s = reds[0] + reds[1] + reds[2] + reds[3];

    const float inv = 1.f / s;
    union { unsigned short u[8]; f16x8 w; } t;
#pragma unroll
    for (int i = 0; i < 8; ++i) t.u[i] = f2h(v[i] * inv);
    *(f16x8*)((unsigned short*)srow + tid * 8) = t.w;
}

extern "C" void kernel_launch(void* const* d_in, const int* in_sizes, int n_in,
                              void* d_out, int out_size, void* d_ws, size_t ws_size,
                              hipStream_t stream)
{
    const float* x  = (const float*)d_in[0];
    const float* wq = (const float*)d_in[1];
    const float* wk = (const float*)d_in[2];
    const float* wv = (const float*)d_in[3];
    float* out = (float*)d_out;

    // sizes (halves unless noted): xh 16.78MB, wh 6.29MB, q/k/vt 16.78MB each
    // batched: [sc fp32 67.1MB | q | k | vt] = 117.4MB  (sc aliases xh+wh)
    // looped:  [xh+wh 23.07MB (sc fp32 16.78 aliases xh) | q | k | vt] = 73.4MB
    char* base = (char*)d_ws;
    const bool batched = (ws_size >= 117440512UL);

    unsigned short* xh = (unsigned short*)base;
    unsigned short* wh = (unsigned short*)(base + 16777216);
    float*          sc = (float*)base;
    unsigned short* q  = (unsigned short*)(base + (batched ? 67108864 : 23068672));
    unsigned short* k  = q + 8388608;
    unsigned short* vt = k + 8388608;

    // 0) conversions
    cvt1<<<4096, 256, 0, stream>>>(x, xh);                        // 8.4M elems
    cvt3<<<dim3(512, 1, 3), 256, 0, stream>>>(wq, wk, wv, wh);    // 3x1M elems

    // 1) projections
    // q,k: M=8192 N=1024 K=1024, z in {wq,wk} and {q,k} (contiguous buffers)
    gemm16<0><<<dim3(8, 64, 2), 256, 0, stream>>>(
        xh, wh, q, 1024, 1024, 1024, 1024, 0L, 1048576L, 8388608L);
    // vt: transpose epilogue; sCz = per-batch stride D*S
    gemm16<1><<<dim3(8, 64, 1), 256, 0, stream>>>(
        xh, wh + 2097152, vt, 1024, 1024, 1024, 2048, 0L, 0L, 2097152L);

    if (batched) {
        // 2) scores: M=N=2048 K=1024, z=batch
        gemm16<2><<<dim3(16, 16, 4), 256, 0, stream>>>(
            q, k, sc, 1024, 1024, 1024, 2048, 2097152L, 2097152L, 4194304L);
        // 3) softmax in place (8192 rows)
        softmax_ip<<<8192, 256, 0, stream>>>(sc);
        // 4) out: M=2048 N=1024 K=2048; A=attn fp16 pitch 4096 halves
        gemm16<2><<<dim3(8, 16, 4), 256, 0, stream>>>(
            (const unsigned short*)sc, vt, out, 2048, 4096, 2048, 1024,
            8388608L, 2097152L, 2097152L);
    } else {
        for (int b = 0; b < 4; ++b) {
            gemm16<2><<<dim3(16, 16, 1), 256, 0, stream>>>(
                q + (long)b * 2097152, k + (long)b * 2097152, sc,
                1024, 1024, 1024, 2048, 0L, 0L, 0L);
            softmax_ip<<<2048, 256, 0, stream>>>(sc);
            gemm16<2><<<dim3(8, 16, 1), 256, 0, stream>>>(
                (const unsigned short*)sc, vt + (long)b * 2097152,
                out + (long)b * 2097152, 2048, 4096, 2048, 1024, 0L, 0L, 0L);
        }
    }
}

// Round 4
// 263.578 us; speedup vs baseline: 2.0410x; 1.2473x over previous
//
#include <hip/hip_runtime.h>
#include <hip/hip_bf16.h>
#include <stdint.h>

// ---------------------------------------------------------------------------
// Self-attention, B=4 S=2048 D=1024, fp32 in/out, fp16 MFMA compute.
//   0) cvt: x -> xh fp16, w_q/w_k/w_v -> wh fp16 (packed)
//   1) one dispatch z=3: z<2 -> q,k fp16 row-major; z==2 -> vt[b][d][s]
//   2) scores = q_b @ k_b^T (fp32, z=batch)
//   3) softmax rows in place (fp32 row -> fp16 row, pitch 4096 halves)
//   4) out_b = attn_b @ vt_b^T (fp32)
// GEMM: 128x128 tile, BK=64 (32 KB LDS), 4 waves (2x2), 4x4 MFMA 16x16x32_f16
// per wave per 32-k step (2 steps/iter). global_load_lds width=16; XOR chunk
// swizzle (8 chunks/128B row) keeps ds_read_b128 conflict-free.
// GRID IS bm-FASTEST: block id % 8 = bm % 8 -> same-XCD blocks share the A
// row-panel in their private L2 (R3 measured 8x A over-fetch with bn-fastest:
// FETCH 150 MB vs 19 MB unique).
// ---------------------------------------------------------------------------

typedef __attribute__((ext_vector_type(8))) _Float16 f16x8;
typedef __attribute__((ext_vector_type(4))) float f32x4;
typedef __attribute__((ext_vector_type(4))) unsigned short u16x4;

__device__ inline unsigned short f2h(float f) {
    union { _Float16 h; unsigned short u; } x;
    x.h = (_Float16)f;   // RNE
    return x.u;
}

__device__ inline void async16(const unsigned short* g, unsigned short* l) {
    __builtin_amdgcn_global_load_lds(
        (__attribute__((address_space(1))) void*)g,
        (__attribute__((address_space(3))) void*)l, 16, 0, 0);
}

// MODE 0: fused projection. z<2 -> fp16 row-major into C (+ z*sCz, ldC);
//         z==2 -> vt transpose into C2 (vt[b][d][s], ld 2048, bstride 2^21).
// MODE 1: fp32 row-major into C.
template <int MODE>
__global__ __launch_bounds__(256)
void gemm16(const unsigned short* __restrict__ A,
            const unsigned short* __restrict__ B,
            void* __restrict__ C, void* __restrict__ C2,
            int K, int ldA, int ldB, int ldC,
            long sAz, long sBz, long sCz)
{
    __shared__ __align__(16) unsigned short smem[2 * 128 * 64];  // 32 KB
    unsigned short* As = smem;
    unsigned short* Bs = smem + 128 * 64;

    const int tid  = threadIdx.x;
    const int lane = tid & 63;
    const int wave = tid >> 6;
    const int wr   = wave >> 1, wc = wave & 1;
    const int quad = lane >> 4, lrow = lane & 15;
    const int bm   = blockIdx.x, bn = blockIdx.y, z = blockIdx.z;  // bm fastest!

    const unsigned short* Az = A + (long)z * sAz;
    const unsigned short* Bz = B + (long)z * sBz;

    // staging: tile = 128 rows x 8 chunks(16B); chunk l -> row l>>3, phys l&7,
    // holding logical k-chunk (l&7)^((l>>3)&7). Thread t stages l = t + 256*i.
    const unsigned short* gA[4];
    const unsigned short* gB[4];
#pragma unroll
    for (int i = 0; i < 4; ++i) {
        const int l = tid + 256 * i;
        const int r = l >> 3;
        const int c = (l & 7) ^ (r & 7);
        gA[i] = Az + (long)(bm * 128 + r) * ldA + c * 8;
        gB[i] = Bz + (long)(bn * 128 + r) * ldB + c * 8;
    }

    f32x4 acc[4][4];
#pragma unroll
    for (int i = 0; i < 4; ++i)
#pragma unroll
        for (int j = 0; j < 4; ++j)
            acc[i][j] = f32x4{0.f, 0.f, 0.f, 0.f};

    const int fr = lrow & 7;   // row parity bits for fragment de-swizzle

    for (int k0 = 0; k0 < K; k0 += 64) {
#pragma unroll
        for (int i = 0; i < 4; ++i) async16(gA[i], &As[(tid + 256 * i) * 8]);
#pragma unroll
        for (int i = 0; i < 4; ++i) async16(gB[i], &Bs[(tid + 256 * i) * 8]);
#pragma unroll
        for (int i = 0; i < 4; ++i) { gA[i] += 64; gB[i] += 64; }
        __syncthreads();   // drains vmcnt -> tiles visible

#pragma unroll
        for (int ks = 0; ks < 2; ++ks) {
            const int pc = (((ks << 2) + quad) ^ fr) * 8;
            f16x8 af[4], bf[4];
#pragma unroll
            for (int mt = 0; mt < 4; ++mt)
                af[mt] = *(const f16x8*)&As[(wr * 64 + mt * 16 + lrow) * 64 + pc];
#pragma unroll
            for (int nt = 0; nt < 4; ++nt)
                bf[nt] = *(const f16x8*)&Bs[(wc * 64 + nt * 16 + lrow) * 64 + pc];
#pragma unroll
            for (int mt = 0; mt < 4; ++mt)
#pragma unroll
                for (int nt = 0; nt < 4; ++nt)
                    acc[mt][nt] = __builtin_amdgcn_mfma_f32_16x16x32_f16(
                        af[mt], bf[nt], acc[mt][nt], 0, 0, 0);
        }
        __syncthreads();   // LDS reusable
    }

    const int col_base = bn * 128 + wc * 64;

    if (MODE == 1 || (MODE == 0 && z < 2)) {
        const int row_base = bm * 128 + wr * 64;
        const long zC = (long)z * sCz;
#pragma unroll
        for (int mt = 0; mt < 4; ++mt)
#pragma unroll
            for (int nt = 0; nt < 4; ++nt)
#pragma unroll
                for (int r = 0; r < 4; ++r) {
                    const int row = row_base + mt * 16 + quad * 4 + r;
                    const int col = col_base + nt * 16 + lrow;
                    if (MODE == 1)
                        ((float*)C)[zC + (long)row * ldC + col] = acc[mt][nt][r];
                    else
                        ((unsigned short*)C)[zC + (long)row * ldC + col] =
                            f2h(acc[mt][nt][r]);
                }
    } else {
        // vt transpose: T[col 128][row 64], pitch 72 halves; aliases As/Bs
        // (safe: trailing barrier of the K-loop drained all ds_reads).
        unsigned short* T = smem;   // needs 128*72 = 9216 halves <= 16384
#pragma unroll
        for (int p = 0; p < 2; ++p) {
            __syncthreads();
            if (wr == p) {
#pragma unroll
                for (int mt = 0; mt < 4; ++mt)
#pragma unroll
                    for (int nt = 0; nt < 4; ++nt) {
                        const int row_l = mt * 16 + quad * 4;
                        const int col_l = wc * 64 + nt * 16 + lrow;
                        u16x4 pk = {f2h(acc[mt][nt][0]), f2h(acc[mt][nt][1]),
                                    f2h(acc[mt][nt][2]), f2h(acc[mt][nt][3])};
                        *(u16x4*)&T[col_l * 72 + row_l] = pk;
                    }
            }
            __syncthreads();
            // copy out: thread covers 32 halves of one d-row, coalesced
            const int c  = tid >> 1;
            const int j0 = (tid & 1) * 32;
            const int tok0 = bm * 128 + p * 64;
            const int bb = tok0 >> 11;           // batch (S=2048)
            const int s0 = (tok0 & 2047) + j0;
            unsigned short* dst = (unsigned short*)C2 + (long)bb * 2097152 +
                                  (long)(bn * 128 + c) * 2048 + s0;
            const unsigned short* srcT = &T[c * 72 + j0];
#pragma unroll
            for (int i = 0; i < 4; ++i)
                *(f16x8*)(dst + i * 8) = *(const f16x8*)(srcT + i * 8);
        }
    }
}

// fp32 -> fp16, 8 elems/thread, exact grid
__global__ __launch_bounds__(256)
void cvt1(const float* __restrict__ s, unsigned short* __restrict__ d)
{
    const long i = ((long)blockIdx.x * 256 + threadIdx.x) * 8;
    f32x4 a = *(const f32x4*)(s + i);
    f32x4 b = *(const f32x4*)(s + i + 4);
    union { unsigned short u[8]; f16x8 v; } t;
#pragma unroll
    for (int j = 0; j < 4; ++j) { t.u[j] = f2h(a[j]); t.u[4 + j] = f2h(b[j]); }
    *(f16x8*)(d + i) = t.v;
}

__global__ __launch_bounds__(256)
void cvt3(const float* __restrict__ s0, const float* __restrict__ s1,
          const float* __restrict__ s2, unsigned short* __restrict__ d)
{
    const int z = blockIdx.z;
    const float* s = (z == 0) ? s0 : (z == 1) ? s1 : s2;
    const long i = ((long)blockIdx.x * 256 + threadIdx.x) * 8;
    f32x4 a = *(const f32x4*)(s + i);
    f32x4 b = *(const f32x4*)(s + i + 4);
    union { unsigned short u[8]; f16x8 v; } t;
#pragma unroll
    for (int j = 0; j < 4; ++j) { t.u[j] = f2h(a[j]); t.u[4 + j] = f2h(b[j]); }
    *(f16x8*)(d + (long)z * 1048576 + i) = t.v;
}

// in-place row softmax: reads 2048 fp32, writes 2048 fp16 at same row base.
__global__ __launch_bounds__(256)
void softmax_ip(float* __restrict__ sc)
{
    const long row = blockIdx.x;
    float* srow = sc + row * 2048;
    const int tid = threadIdx.x;

    f32x4 a = *(const f32x4*)(srow + tid * 8);
    f32x4 b = *(const f32x4*)(srow + tid * 8 + 4);
    float v[8];
#pragma unroll
    for (int i = 0; i < 4; ++i) { v[i] = a[i]; v[4 + i] = b[i]; }

    float m = v[0];
#pragma unroll
    for (int i = 1; i < 8; ++i) m = fmaxf(m, v[i]);
#pragma unroll
    for (int off = 32; off; off >>= 1) m = fmaxf(m, __shfl_xor(m, off));

    __shared__ float redm[4], reds[4];
    if ((tid & 63) == 0) redm[tid >> 6] = m;
    __syncthreads();
    m = fmaxf(fmaxf(redm[0], redm[1]), fmaxf(redm[2], redm[3]));

    float s = 0.f;
#pragma unroll
    for (int i = 0; i < 8; ++i) { v[i] = __expf(v[i] - m); s += v[i]; }
#pragma unroll
    for (int off = 32; off; off >>= 1) s += __shfl_xor(s, off);
    if ((tid & 63) == 0) reds[tid >> 6] = s;
    __syncthreads();
    s = reds[0] + reds[1] + reds[2] + reds[3];

    const float inv = 1.f / s;
    union { unsigned short u[8]; f16x8 w; } t;
#pragma unroll
    for (int i = 0; i < 8; ++i) t.u[i] = f2h(v[i] * inv);
    *(f16x8*)((unsigned short*)srow + tid * 8) = t.w;
}

extern "C" void kernel_launch(void* const* d_in, const int* in_sizes, int n_in,
                              void* d_out, int out_size, void* d_ws, size_t ws_size,
                              hipStream_t stream)
{
    const float* x  = (const float*)d_in[0];
    const float* wq = (const float*)d_in[1];
    const float* wk = (const float*)d_in[2];
    const float* wv = (const float*)d_in[3];
    float* out = (float*)d_out;

    // batched: [sc fp32 67.1MB (aliases xh|wh) | q | k | vt] = 117.4MB
    // looped:  [xh|wh 23.07MB (sc fp32 16.78 aliases xh) | q | k | vt] = 73.4MB
    char* base = (char*)d_ws;
    const bool batched = (ws_size >= 117440512UL);

    unsigned short* xh = (unsigned short*)base;
    unsigned short* wh = (unsigned short*)(base + 16777216);
    float*          sc = (float*)base;
    unsigned short* q  = (unsigned short*)(base + (batched ? 67108864 : 23068672));
    unsigned short* k  = q + 8388608;
    unsigned short* vt = k + 8388608;

    // 0) conversions
    cvt1<<<4096, 256, 0, stream>>>(x, xh);
    cvt3<<<dim3(512, 1, 3), 256, 0, stream>>>(wq, wk, wv, wh);

    // 1) fused projections: M=8192 N=1024 K=1024; z=0,1 -> q,k; z=2 -> vt
    gemm16<0><<<dim3(64, 8, 3), 256, 0, stream>>>(
        xh, wh, q, vt, 1024, 1024, 1024, 1024, 0L, 1048576L, 8388608L);

    if (batched) {
        // 2) scores: M=N=2048 K=1024, z=batch
        gemm16<1><<<dim3(16, 16, 4), 256, 0, stream>>>(
            q, k, sc, nullptr, 1024, 1024, 1024, 2048,
            2097152L, 2097152L, 4194304L);
        // 3) softmax in place (8192 rows)
        softmax_ip<<<8192, 256, 0, stream>>>(sc);
        // 4) out: M=2048 N=1024 K=2048; A=attn fp16 pitch 4096 halves
        gemm16<1><<<dim3(16, 8, 4), 256, 0, stream>>>(
            (const unsigned short*)sc, vt, out, nullptr, 2048, 4096, 2048, 1024,
            8388608L, 2097152L, 2097152L);
    } else {
        for (int b = 0; b < 4; ++b) {
            gemm16<1><<<dim3(16, 16, 1), 256, 0, stream>>>(
                q + (long)b * 2097152, k + (long)b * 2097152, sc, nullptr,
                1024, 1024, 1024, 2048, 0L, 0L, 0L);
            softmax_ip<<<2048, 256, 0, stream>>>(sc);
            gemm16<1><<<dim3(16, 8, 1), 256, 0, stream>>>(
                (const unsigned short*)sc, vt + (long)b * 2097152,
                out + (long)b * 2097152, nullptr,
                2048, 4096, 2048, 1024, 0L, 0L, 0L);
        }
    }
}

// Round 5
// 261.789 us; speedup vs baseline: 2.0549x; 1.0068x over previous
//
#include <hip/hip_runtime.h>
#include <hip/hip_bf16.h>
#include <stdint.h>

// ---------------------------------------------------------------------------
// Self-attention, B=4 S=2048 D=1024, fp32 in/out, fp16 MFMA compute.
//   0) cvt (one dispatch): x -> xh fp16; w_q/w_k/w_v -> wh fp16 (packed)
//   1) one dispatch z=3: z<2 -> q,k fp16 row-major; z==2 -> vt[b][d][s]
//   2) scores = q_b @ k_b^T (fp32, z=batch, 128x128 tiles)
//   3) softmax rows in place (fp32 row -> fp16 row, pitch 4096 halves)
//   4) out_b = attn_b @ vt_b^T (fp32, 128x64 tiles -> 1024 blocks = 4/CU;
//      R4 measured 2 blocks/CU at 128x128 -> 506 TF, below overlap knee)
// GEMM: 128xBN tile, BK=64, 4 waves (2x2), MFMA 16x16x32_f16.
// global_load_lds width=16; XOR chunk swizzle keeps ds_read_b128
// conflict-free. bm-fastest grid: same-XCD blocks share the A row-panel
// (R3->R4: proj FETCH 150 -> 42 MB).
// ---------------------------------------------------------------------------

typedef __attribute__((ext_vector_type(8))) _Float16 f16x8;
typedef __attribute__((ext_vector_type(4))) float f32x4;
typedef __attribute__((ext_vector_type(4))) unsigned short u16x4;

__device__ inline unsigned short f2h(float f) {
    union { _Float16 h; unsigned short u; } x;
    x.h = (_Float16)f;   // RNE
    return x.u;
}

__device__ inline void async16(const unsigned short* g, unsigned short* l) {
    __builtin_amdgcn_global_load_lds(
        (__attribute__((address_space(1))) void*)g,
        (__attribute__((address_space(3))) void*)l, 16, 0, 0);
}

// MODE 0: fused projection (BN=128). z<2 -> fp16 row-major into C (+z*sCz);
//         z==2 -> vt transpose into C2 (vt[b][d][s], ld 2048, bstride 2^21).
// MODE 1: fp32 row-major into C. BN in {64,128} = N-tile width.
template <int MODE, int BN>
__global__ __launch_bounds__(256)
void gemm16(const unsigned short* __restrict__ A,
            const unsigned short* __restrict__ B,
            void* __restrict__ C, void* __restrict__ C2,
            int K, int ldA, int ldB, int ldC,
            long sAz, long sBz, long sCz)
{
    constexpr int NT = BN / 32;            // MFMA col-tiles per wave
    __shared__ __align__(16) unsigned short smem[128 * 64 + BN * 64];
    unsigned short* As = smem;
    unsigned short* Bs = smem + 128 * 64;

    const int tid  = threadIdx.x;
    const int lane = tid & 63;
    const int wave = tid >> 6;
    const int wr   = wave >> 1, wc = wave & 1;
    const int quad = lane >> 4, lrow = lane & 15;
    const int bm   = blockIdx.x, bn = blockIdx.y, z = blockIdx.z;  // bm fastest

    const unsigned short* Az = A + (long)z * sAz;
    const unsigned short* Bz = B + (long)z * sBz;

    // staging: tile rows x 8 chunks(16B); chunk l -> row l>>3, phys l&7,
    // holding logical k-chunk (l&7)^((l>>3)&7). Thread t stages l = t+256*i.
    const unsigned short* gA[4];
    const unsigned short* gB[4];
#pragma unroll
    for (int i = 0; i < 4; ++i) {
        const int l = tid + 256 * i;
        const int r = l >> 3;
        const int c = (l & 7) ^ (r & 7);
        gA[i] = Az + (long)(bm * 128 + r) * ldA + c * 8;
    }
#pragma unroll
    for (int i = 0; i < NT; ++i) {
        const int l = tid + 256 * i;
        const int r = l >> 3;
        const int c = (l & 7) ^ (r & 7);
        gB[i] = Bz + (long)(bn * BN + r) * ldB + c * 8;
    }

    f32x4 acc[4][4];
#pragma unroll
    for (int i = 0; i < 4; ++i)
#pragma unroll
        for (int j = 0; j < NT; ++j)
            acc[i][j] = f32x4{0.f, 0.f, 0.f, 0.f};

    const int fr = lrow & 7;   // row bits for fragment de-swizzle

    for (int k0 = 0; k0 < K; k0 += 64) {
#pragma unroll
        for (int i = 0; i < 4; ++i) async16(gA[i], &As[(tid + 256 * i) * 8]);
#pragma unroll
        for (int i = 0; i < NT; ++i) async16(gB[i], &Bs[(tid + 256 * i) * 8]);
#pragma unroll
        for (int i = 0; i < 4; ++i) gA[i] += 64;
#pragma unroll
        for (int i = 0; i < NT; ++i) gB[i] += 64;
        __syncthreads();   // drains vmcnt -> tiles visible

#pragma unroll
        for (int ks = 0; ks < 2; ++ks) {
            const int pc = (((ks << 2) + quad) ^ fr) * 8;
            f16x8 af[4], bf[4];
#pragma unroll
            for (int mt = 0; mt < 4; ++mt)
                af[mt] = *(const f16x8*)&As[(wr * 64 + mt * 16 + lrow) * 64 + pc];
#pragma unroll
            for (int nt = 0; nt < NT; ++nt)
                bf[nt] = *(const f16x8*)&Bs[(wc * (BN / 2) + nt * 16 + lrow) * 64 + pc];
#pragma unroll
            for (int mt = 0; mt < 4; ++mt)
#pragma unroll
                for (int nt = 0; nt < NT; ++nt)
                    acc[mt][nt] = __builtin_amdgcn_mfma_f32_16x16x32_f16(
                        af[mt], bf[nt], acc[mt][nt], 0, 0, 0);
        }
        __syncthreads();   // LDS reusable
    }

    const int col_base = bn * BN + wc * (BN / 2);

    if (MODE == 1 || (MODE == 0 && z < 2)) {
        const int row_base = bm * 128 + wr * 64;
        const long zC = (long)z * sCz;
#pragma unroll
        for (int mt = 0; mt < 4; ++mt)
#pragma unroll
            for (int nt = 0; nt < NT; ++nt)
#pragma unroll
                for (int r = 0; r < 4; ++r) {
                    const int row = row_base + mt * 16 + quad * 4 + r;
                    const int col = col_base + nt * 16 + lrow;
                    if (MODE == 1)
                        ((float*)C)[zC + (long)row * ldC + col] = acc[mt][nt][r];
                    else
                        ((unsigned short*)C)[zC + (long)row * ldC + col] =
                            f2h(acc[mt][nt][r]);
                }
    } else {
        // vt transpose (BN=128 only): T[col 128][row 64], pitch 72 halves
        // (144B rows keep 16B alignment); aliases As/Bs after final barrier.
        unsigned short* T = smem;   // 128*72 = 9216 halves <= 16384
#pragma unroll
        for (int p = 0; p < 2; ++p) {
            __syncthreads();
            if (wr == p) {
#pragma unroll
                for (int mt = 0; mt < 4; ++mt)
#pragma unroll
                    for (int nt = 0; nt < NT; ++nt) {
                        const int row_l = mt * 16 + quad * 4;
                        const int col_l = wc * (BN / 2) + nt * 16 + lrow;
                        u16x4 pk = {f2h(acc[mt][nt][0]), f2h(acc[mt][nt][1]),
                                    f2h(acc[mt][nt][2]), f2h(acc[mt][nt][3])};
                        *(u16x4*)&T[col_l * 72 + row_l] = pk;
                    }
            }
            __syncthreads();
            // copy out: thread covers 32 halves of one d-row, coalesced
            const int c  = tid >> 1;
            const int j0 = (tid & 1) * 32;
            const int tok0 = bm * 128 + p * 64;
            const int bb = tok0 >> 11;           // batch (S=2048)
            const int s0 = (tok0 & 2047) + j0;
            unsigned short* dst = (unsigned short*)C2 + (long)bb * 2097152 +
                                  (long)(bn * 128 + c) * 2048 + s0;
            const unsigned short* srcT = &T[c * 72 + j0];
#pragma unroll
            for (int i = 0; i < 4; ++i)
                *(f16x8*)(dst + i * 8) = *(const f16x8*)(srcT + i * 8);
        }
    }
}

// fused fp32 -> fp16 conversion: blocks [0,4096) -> x, [4096,5632) -> weights
__global__ __launch_bounds__(256)
void cvt_all(const float* __restrict__ x, const float* __restrict__ w0,
             const float* __restrict__ w1, const float* __restrict__ w2,
             unsigned short* __restrict__ xh, unsigned short* __restrict__ wh)
{
    const int bid = blockIdx.x;
    const float* s;
    unsigned short* d;
    long i;
    if (bid < 4096) {
        s = x; d = xh;
        i = ((long)bid * 256 + threadIdx.x) * 8;
    } else {
        const int wid = bid - 4096;          // [0,1536)
        const int w = wid >> 9;              // weight index
        s = (w == 0) ? w0 : (w == 1) ? w1 : w2;
        d = wh + (long)w * 1048576;
        i = ((long)(wid & 511) * 256 + threadIdx.x) * 8;
    }
    f32x4 a = *(const f32x4*)(s + i);
    f32x4 b = *(const f32x4*)(s + i + 4);
    union { unsigned short u[8]; f16x8 v; } t;
#pragma unroll
    for (int j = 0; j < 4; ++j) { t.u[j] = f2h(a[j]); t.u[4 + j] = f2h(b[j]); }
    *(f16x8*)(d + i) = t.v;
}

// in-place row softmax: reads 2048 fp32, writes 2048 fp16 at same row base.
__global__ __launch_bounds__(256)
void softmax_ip(float* __restrict__ sc)
{
    const long row = blockIdx.x;
    float* srow = sc + row * 2048;
    const int tid = threadIdx.x;

    f32x4 a = *(const f32x4*)(srow + tid * 8);
    f32x4 b = *(const f32x4*)(srow + tid * 8 + 4);
    float v[8];
#pragma unroll
    for (int i = 0; i < 4; ++i) { v[i] = a[i]; v[4 + i] = b[i]; }

    float m = v[0];
#pragma unroll
    for (int i = 1; i < 8; ++i) m = fmaxf(m, v[i]);
#pragma unroll
    for (int off = 32; off; off >>= 1) m = fmaxf(m, __shfl_xor(m, off));

    __shared__ float redm[4], reds[4];
    if ((tid & 63) == 0) redm[tid >> 6] = m;
    __syncthreads();
    m = fmaxf(fmaxf(redm[0], redm[1]), fmaxf(redm[2], redm[3]));

    float s = 0.f;
#pragma unroll
    for (int i = 0; i < 8; ++i) { v[i] = __expf(v[i] - m); s += v[i]; }
#pragma unroll
    for (int off = 32; off; off >>= 1) s += __shfl_xor(s, off);
    if ((tid & 63) == 0) reds[tid >> 6] = s;
    __syncthreads();
    s = reds[0] + reds[1] + reds[2] + reds[3];

    const float inv = 1.f / s;
    union { unsigned short u[8]; f16x8 w; } t;
#pragma unroll
    for (int i = 0; i < 8; ++i) t.u[i] = f2h(v[i] * inv);
    *(f16x8*)((unsigned short*)srow + tid * 8) = t.w;
}

extern "C" void kernel_launch(void* const* d_in, const int* in_sizes, int n_in,
                              void* d_out, int out_size, void* d_ws, size_t ws_size,
                              hipStream_t stream)
{
    const float* x  = (const float*)d_in[0];
    const float* wq = (const float*)d_in[1];
    const float* wk = (const float*)d_in[2];
    const float* wv = (const float*)d_in[3];
    float* out = (float*)d_out;

    // batched: [sc fp32 67.1MB (aliases xh|wh) | q | k | vt] = 117.4MB
    // looped:  [xh|wh 23.07MB (sc fp32 16.78 aliases xh) | q | k | vt] = 73.4MB
    char* base = (char*)d_ws;
    const bool batched = (ws_size >= 117440512UL);

    unsigned short* xh = (unsigned short*)base;
    unsigned short* wh = (unsigned short*)(base + 16777216);
    float*          sc = (float*)base;
    unsigned short* q  = (unsigned short*)(base + (batched ? 67108864 : 23068672));
    unsigned short* k  = q + 8388608;
    unsigned short* vt = k + 8388608;

    // 0) conversions (single dispatch)
    cvt_all<<<5632, 256, 0, stream>>>(x, wq, wk, wv, xh, wh);

    // 1) fused projections: M=8192 N=1024 K=1024; z=0,1 -> q,k; z=2 -> vt
    gemm16<0, 128><<<dim3(64, 8, 3), 256, 0, stream>>>(
        xh, wh, q, vt, 1024, 1024, 1024, 1024, 0L, 1048576L, 8388608L);

    if (batched) {
        // 2) scores: M=N=2048 K=1024, z=batch (128x128, 1024 blocks)
        gemm16<1, 128><<<dim3(16, 16, 4), 256, 0, stream>>>(
            q, k, sc, nullptr, 1024, 1024, 1024, 2048,
            2097152L, 2097152L, 4194304L);
        // 3) softmax in place (8192 rows)
        softmax_ip<<<8192, 256, 0, stream>>>(sc);
        // 4) out: M=2048 N=1024 K=2048 (128x64 tiles -> 1024 blocks)
        gemm16<1, 64><<<dim3(16, 16, 4), 256, 0, stream>>>(
            (const unsigned short*)sc, vt, out, nullptr, 2048, 4096, 2048, 1024,
            8388608L, 2097152L, 2097152L);
    } else {
        for (int b = 0; b < 4; ++b) {
            gemm16<1, 128><<<dim3(16, 16, 1), 256, 0, stream>>>(
                q + (long)b * 2097152, k + (long)b * 2097152, sc, nullptr,
                1024, 1024, 1024, 2048, 0L, 0L, 0L);
            softmax_ip<<<2048, 256, 0, stream>>>(sc);
            gemm16<1, 64><<<dim3(16, 16, 1), 256, 0, stream>>>(
                (const unsigned short*)sc, vt + (long)b * 2097152,
                out + (long)b * 2097152, nullptr,
                2048, 4096, 2048, 1024, 0L, 0L, 0L);
        }
    }
}

// Round 6
// 243.889 us; speedup vs baseline: 2.2057x; 1.0734x over previous
//
#include <hip/hip_runtime.h>
#include <hip/hip_bf16.h>
#include <stdint.h>

// ---------------------------------------------------------------------------
// Self-attention, B=4 S=2048 D=1024, fp32 in/out, fp16 MFMA compute.
//   0) cvt: x -> xh fp16; w_q/w_k/w_v -> wh fp16 (one dispatch)
//   1) proj z=3: z<2 -> q,k fp16 row-major; z==2 -> vt[b][d][s] (LDS transp.)
//   2) scores = q_b @ k_b^T -> fp16 (z=batch)   [fp16 scores: ulp<=0.03 at
//      |s|<=45 -> ~+0.006 output err; measured margin 3x allows it]
//   3) softmax rows in place fp16->fp16
//   4) out_b = attn_b @ vt_b^T (fp32)
// GEMM: 512 threads, 256xBN tile, BK=64, 8 waves (4x2), MFMA 16x16x32_f16.
// 48 KB LDS (BN=128) -> 187 B staged per MFMA (-27% vs R5) and proj runs
// 3 blocks/CU (24 waves). global_load_lds width=16; XOR chunk swizzle keeps
// ds_read_b128 conflict-free. bm-fastest grid: same-XCD blocks share the A
// row-panel in their private L2 (R3->R4: FETCH 150 -> 42 MB).
// ---------------------------------------------------------------------------

typedef __attribute__((ext_vector_type(8))) _Float16 f16x8;
typedef __attribute__((ext_vector_type(4))) float f32x4;
typedef __attribute__((ext_vector_type(4))) unsigned short u16x4;

__device__ inline unsigned short f2h(float f) {
    union { _Float16 h; unsigned short u; } x;
    x.h = (_Float16)f;   // RNE
    return x.u;
}
__device__ inline float h2f(unsigned short u) {
    union { unsigned short u; _Float16 h; } x;
    x.u = u;
    return (float)x.h;
}

__device__ inline void async16(const unsigned short* g, unsigned short* l) {
    __builtin_amdgcn_global_load_lds(
        (__attribute__((address_space(1))) void*)g,
        (__attribute__((address_space(3))) void*)l, 16, 0, 0);
}

// MODE 0: proj (BN=128): z<2 -> fp16 row-major into C (+z*sCz);
//         z==2 -> vt transpose into C2 (vt[b][d][s], ld 2048, bstride 2^21).
// MODE 1: fp16 row-major into C (scores).
// MODE 2: fp32 row-major into C (final out).
// Tile: BM=256 rows x BN cols, BK=64. 8 waves: wr=wave>>1 (4), wc=wave&1 (2).
template <int MODE, int BN>
__global__ __launch_bounds__(512)
void gemm512(const unsigned short* __restrict__ A,
             const unsigned short* __restrict__ B,
             void* __restrict__ C, void* __restrict__ C2,
             int K, int ldA, int ldB, int ldC,
             long sAz, long sBz, long sCz)
{
    constexpr int NT = BN / 32;           // MFMA col-tiles per wave
    constexpr int BI = BN / 64;           // B staging chunks per thread
    __shared__ __align__(16) unsigned short smem[256 * 64 + BN * 64];
    unsigned short* As = smem;
    unsigned short* Bs = smem + 256 * 64;

    const int tid  = threadIdx.x;
    const int lane = tid & 63;
    const int wave = tid >> 6;
    const int wr   = wave >> 1, wc = wave & 1;
    const int quad = lane >> 4, lrow = lane & 15;
    const int bm   = blockIdx.x, bn = blockIdx.y, z = blockIdx.z;  // bm fastest

    const unsigned short* Az = A + (long)z * sAz;
    const unsigned short* Bz = B + (long)z * sBz;

    // staging: 16B chunks; chunk l -> row l>>3, phys slot l&7, holding logical
    // k-chunk (l&7)^(row&7) (XOR swizzle). Thread t stages l = t + 512*i.
    const unsigned short* gA[4];
    const unsigned short* gB[BI];
#pragma unroll
    for (int i = 0; i < 4; ++i) {
        const int l = tid + 512 * i;
        const int r = l >> 3;
        const int c = (l & 7) ^ (r & 7);
        gA[i] = Az + (long)(bm * 256 + r) * ldA + c * 8;
    }
#pragma unroll
    for (int i = 0; i < BI; ++i) {
        const int l = tid + 512 * i;
        const int r = l >> 3;
        const int c = (l & 7) ^ (r & 7);
        gB[i] = Bz + (long)(bn * BN + r) * ldB + c * 8;
    }

    f32x4 acc[4][NT];
#pragma unroll
    for (int i = 0; i < 4; ++i)
#pragma unroll
        for (int j = 0; j < NT; ++j)
            acc[i][j] = f32x4{0.f, 0.f, 0.f, 0.f};

    const int fr = lrow & 7;   // row bits for fragment de-swizzle

    for (int k0 = 0; k0 < K; k0 += 64) {
#pragma unroll
        for (int i = 0; i < 4; ++i) async16(gA[i], &As[(tid + 512 * i) * 8]);
#pragma unroll
        for (int i = 0; i < BI; ++i) async16(gB[i], &Bs[(tid + 512 * i) * 8]);
#pragma unroll
        for (int i = 0; i < 4; ++i) gA[i] += 64;
#pragma unroll
        for (int i = 0; i < BI; ++i) gB[i] += 64;
        __syncthreads();   // drains vmcnt -> tiles visible

#pragma unroll
        for (int ks = 0; ks < 2; ++ks) {
            const int pc = (((ks << 2) + quad) ^ fr) * 8;
            f16x8 af[4], bf[NT];
#pragma unroll
            for (int mt = 0; mt < 4; ++mt)
                af[mt] = *(const f16x8*)&As[(wr * 64 + mt * 16 + lrow) * 64 + pc];
#pragma unroll
            for (int nt = 0; nt < NT; ++nt)
                bf[nt] = *(const f16x8*)&Bs[(wc * (BN / 2) + nt * 16 + lrow) * 64 + pc];
#pragma unroll
            for (int mt = 0; mt < 4; ++mt)
#pragma unroll
                for (int nt = 0; nt < NT; ++nt)
                    acc[mt][nt] = __builtin_amdgcn_mfma_f32_16x16x32_f16(
                        af[mt], bf[nt], acc[mt][nt], 0, 0, 0);
        }
        __syncthreads();   // LDS reusable
    }

    const int col_base = bn * BN + wc * (BN / 2);

    if (MODE != 0 || z < 2) {
        const int row_base = bm * 256 + wr * 64;
        const long zC = (long)z * sCz;
#pragma unroll
        for (int mt = 0; mt < 4; ++mt)
#pragma unroll
            for (int nt = 0; nt < NT; ++nt)
#pragma unroll
                for (int r = 0; r < 4; ++r) {
                    const int row = row_base + mt * 16 + quad * 4 + r;
                    const int col = col_base + nt * 16 + lrow;
                    if (MODE == 2)
                        ((float*)C)[zC + (long)row * ldC + col] = acc[mt][nt][r];
                    else
                        ((unsigned short*)C)[zC + (long)row * ldC + col] =
                            f2h(acc[mt][nt][r]);
                }
    } else {
        // vt transpose (BN=128): 4 phases of 64 token-rows. T[col 128][row 64]
        // pitch 72 halves (144B rows keep 16B align); aliases As (post-barrier).
        unsigned short* T = smem;   // 128*72 = 9216 halves <= 16384
#pragma unroll
        for (int p = 0; p < 4; ++p) {
            __syncthreads();
            if (wr == p) {
#pragma unroll
                for (int mt = 0; mt < 4; ++mt)
#pragma unroll
                    for (int nt = 0; nt < NT; ++nt) {
                        const int row_l = mt * 16 + quad * 4;     // within band
                        const int col_l = wc * 64 + nt * 16 + lrow;
                        u16x4 pk = {f2h(acc[mt][nt][0]), f2h(acc[mt][nt][1]),
                                    f2h(acc[mt][nt][2]), f2h(acc[mt][nt][3])};
                        *(u16x4*)&T[col_l * 72 + row_l] = pk;
                    }
            }
            __syncthreads();
            // copy out: 128 cols x 64 rows = 8192 halves = 512 thr x 16
            const int c  = tid >> 2;
            const int j0 = (tid & 3) * 16;
            const int tok0 = bm * 256 + p * 64;   // 256-row tile never crosses
            const int bb = tok0 >> 11;            // a batch boundary (2048%256=0)
            const int s0 = (tok0 & 2047) + j0;
            unsigned short* dst = (unsigned short*)C2 + (long)bb * 2097152 +
                                  (long)(bn * 128 + c) * 2048 + s0;
            const unsigned short* srcT = &T[c * 72 + j0];
            *(f16x8*)dst = *(const f16x8*)srcT;
            *(f16x8*)(dst + 8) = *(const f16x8*)(srcT + 8);
        }
    }
}

// fused fp32 -> fp16 conversion: blocks [0,4096) -> x, [4096,5632) -> weights
__global__ __launch_bounds__(256)
void cvt_all(const float* __restrict__ x, const float* __restrict__ w0,
             const float* __restrict__ w1, const float* __restrict__ w2,
             unsigned short* __restrict__ xh, unsigned short* __restrict__ wh)
{
    const int bid = blockIdx.x;
    const float* s;
    unsigned short* d;
    long i;
    if (bid < 4096) {
        s = x; d = xh;
        i = ((long)bid * 256 + threadIdx.x) * 8;
    } else {
        const int wid = bid - 4096;          // [0,1536)
        const int w = wid >> 9;              // weight index
        s = (w == 0) ? w0 : (w == 1) ? w1 : w2;
        d = wh + (long)w * 1048576;
        i = ((long)(wid & 511) * 256 + threadIdx.x) * 8;
    }
    f32x4 a = *(const f32x4*)(s + i);
    f32x4 b = *(const f32x4*)(s + i + 4);
    union { unsigned short u[8]; f16x8 v; } t;
#pragma unroll
    for (int j = 0; j < 4; ++j) { t.u[j] = f2h(a[j]); t.u[4 + j] = f2h(b[j]); }
    *(f16x8*)(d + i) = t.v;
}

// in-place fp16 row softmax: row = 2048 fp16, one block per row.
__global__ __launch_bounds__(256)
void softmax16(unsigned short* __restrict__ sc)
{
    const long row = blockIdx.x;
    unsigned short* srow = sc + row * 2048;
    const int tid = threadIdx.x;

    union { u16x4 p[2]; unsigned short u[8]; } in;
    in.p[0] = *(const u16x4*)(srow + tid * 8);
    in.p[1] = *(const u16x4*)(srow + tid * 8 + 4);
    float v[8];
#pragma unroll
    for (int i = 0; i < 8; ++i) v[i] = h2f(in.u[i]);

    float m = v[0];
#pragma unroll
    for (int i = 1; i < 8; ++i) m = fmaxf(m, v[i]);
#pragma unroll
    for (int off = 32; off; off >>= 1) m = fmaxf(m, __shfl_xor(m, off));

    __shared__ float redm[4], reds[4];
    if ((tid & 63) == 0) redm[tid >> 6] = m;
    __syncthreads();
    m = fmaxf(fmaxf(redm[0], redm[1]), fmaxf(redm[2], redm[3]));

    float s = 0.f;
#pragma unroll
    for (int i = 0; i < 8; ++i) { v[i] = __expf(v[i] - m); s += v[i]; }
#pragma unroll
    for (int off = 32; off; off >>= 1) s += __shfl_xor(s, off);
    if ((tid & 63) == 0) reds[tid >> 6] = s;
    __syncthreads();
    s = reds[0] + reds[1] + reds[2] + reds[3];

    const float inv = 1.f / s;
    union { unsigned short u[8]; f16x8 w; } t;
#pragma unroll
    for (int i = 0; i < 8; ++i) t.u[i] = f2h(v[i] * inv);
    *(f16x8*)(srow + tid * 8) = t.w;
}

extern "C" void kernel_launch(void* const* d_in, const int* in_sizes, int n_in,
                              void* d_out, int out_size, void* d_ws, size_t ws_size,
                              hipStream_t stream)
{
    const float* x  = (const float*)d_in[0];
    const float* wq = (const float*)d_in[1];
    const float* wk = (const float*)d_in[2];
    const float* wv = (const float*)d_in[3];
    float* out = (float*)d_out;

    // batched: [sc fp16 33.5MB (aliases xh 16.8 | wh 6.3)] [q][k][vt] = 83.9MB
    // looped:  [xh|wh 23.1MB (per-batch sc fp16 8.4MB aliases xh)][q][k][vt]
    //          = 73.4MB
    char* base = (char*)d_ws;
    const bool batched = (ws_size >= 88080384UL);   // 84 MB

    unsigned short* xh = (unsigned short*)base;
    unsigned short* wh = (unsigned short*)(base + 16777216);
    unsigned short* sc = (unsigned short*)base;
    unsigned short* q  = (unsigned short*)(base + (batched ? 33554432 : 23068672));
    unsigned short* k  = q + 8388608;
    unsigned short* vt = k + 8388608;

    // 0) conversions (single dispatch)
    cvt_all<<<5632, 256, 0, stream>>>(x, wq, wk, wv, xh, wh);

    // 1) fused projections: M=8192 N=1024 K=1024; z=0,1 -> q,k; z=2 -> vt
    //    grid (32,8,3) = 768 blocks = 3/CU
    gemm512<0, 128><<<dim3(32, 8, 3), 512, 0, stream>>>(
        xh, wh, q, vt, 1024, 1024, 1024, 1024, 0L, 1048576L, 8388608L);

    if (batched) {
        // 2) scores fp16: M=N=2048 K=1024, z=batch; (8,16,4)=512 blocks
        gemm512<1, 128><<<dim3(8, 16, 4), 512, 0, stream>>>(
            q, k, sc, nullptr, 1024, 1024, 1024, 2048,
            2097152L, 2097152L, 4194304L);
        // 3) softmax in place (8192 rows, fp16->fp16)
        softmax16<<<8192, 256, 0, stream>>>(sc);
        // 4) out: M=2048 N=1024 K=2048; 256x64 tiles, (8,16,4)=512 blocks
        gemm512<2, 64><<<dim3(8, 16, 4), 512, 0, stream>>>(
            sc, vt, out, nullptr, 2048, 2048, 2048, 1024,
            4194304L, 2097152L, 2097152L);
    } else {
        for (int b = 0; b < 4; ++b) {
            gemm512<1, 128><<<dim3(8, 16, 1), 512, 0, stream>>>(
                q + (long)b * 2097152, k + (long)b * 2097152, sc, nullptr,
                1024, 1024, 1024, 2048, 0L, 0L, 0L);
            softmax16<<<2048, 256, 0, stream>>>(sc);
            gemm512<2, 64><<<dim3(8, 16, 1), 512, 0, stream>>>(
                sc, vt + (long)b * 2097152, out + (long)b * 2097152, nullptr,
                2048, 2048, 2048, 1024, 0L, 0L, 0L);
        }
    }
}